// Round 8
// baseline (282.231 us; speedup 1.0000x reference)
//
#include <hip/hip_runtime.h>
#include <math.h>

// Problem constants
#define BB   64
#define FC   24
#define NN   1000
#define HID  64
#define EMBD 32
#define TT   48
#define FF   8
#define INSZ 33

// One wave (64 threads) per block; wave owns CPW cells x all 64 hid cols.
#define CPW  16
#define AST  72     // Hbuf stride in bf16 elems (144 B rows, 16B-aligned)
#define XST  40     // Xt stride in bf16 elems (80 B rows, 16B-aligned)

#define NL2E (-1.4426950408889634f)   // -log2(e): folded into r,z weights
#define TL2E ( 2.8853900817779268f)   // 2*log2(e): folded into n weights

typedef __attribute__((ext_vector_type(8))) short bf16x8;
typedef __attribute__((ext_vector_type(4))) float f32x4;

// packed RNE f32->bf16: lo16 = bf16(a), hi16 = bf16(b)
static __device__ __forceinline__ unsigned cvt_pk_bf16(float a, float b) {
    unsigned r;
    asm("v_cvt_pk_bf16_f32 %0, %1, %2" : "=v"(r) : "v"(a), "v"(b));
    return r;
}
static __device__ __forceinline__ bf16x8 mk_bf8(float4 lo, float4 hi, float s) {
    union { unsigned u[4]; bf16x8 v; } r;
    r.u[0] = cvt_pk_bf16(lo.x * s, lo.y * s);
    r.u[1] = cvt_pk_bf16(lo.z * s, lo.w * s);
    r.u[2] = cvt_pk_bf16(hi.x * s, hi.y * s);
    r.u[3] = cvt_pk_bf16(hi.z * s, hi.w * s);
    return r.v;
}

// COMPILER-ONLY fence, zero ISA instructions. Same-wave DS ops execute
// in order in hardware; this stops TBAA-based reordering of mixed-type
// LDS accesses (uint2 h-writes vs bf16x8 mfma-reads) — the R7 bug.
static __device__ __forceinline__ void wave_fence() {
    asm volatile("" ::: "memory");
    __builtin_amdgcn_sched_barrier(0);
}

// NO s_barrier in this kernel: all LDS is wave-private; ordering is
// per-wave in-order DS + wave_fence() against compiler reordering.
__global__ __launch_bounds__(64) __attribute__((amdgpu_waves_per_eu(2)))
void gru_decoder(
    const float* __restrict__ X,    // [B][TT][N][F]
    const float* __restrict__ hn0,  // [B*N][HID]
    const float* __restrict__ xn,   // [B][N][1]
    const float* __restrict__ emb,  // [NEMB][EMBD]
    const float* __restrict__ Wih,  // [3*HID][INSZ]
    const float* __restrict__ Whh,  // [3*HID][HID]
    const float* __restrict__ bih,  // [3*HID]
    const float* __restrict__ bhh,  // [3*HID]
    const float* __restrict__ Wout, // [1][HID]
    const float* __restrict__ bout, // [1]
    float* __restrict__ out)        // [B][FC][N][1]
{
    __shared__ __align__(16) unsigned short Hbuf[CPW * AST];   // 2304 B
    __shared__ __align__(16) unsigned short Xt[2][CPW * XST];  // 2560 B
    __shared__ int idxbuf[(FC + 1) * CPW];                     // 1600 B

    const int lane = threadIdx.x;      // one wave per block
    const int quad = lane >> 4;
    const int l15  = lane & 15;
    const int cell0 = blockIdx.x * CPW;

    // ---- stage idx for steps 0..FC (row FC dups FC-1) ----
    for (int e = lane; e < (FC + 1) * CPW; e += 64) {
        int t = e >> 4, m = e & 15;
        int tt = (t < FC) ? t : FC - 1;
        int cell = cell0 + m;
        int b = cell / NN, n = cell - b * NN;
        idxbuf[e] = (int)X[(((size_t)b * TT + tt) * NN + n) * FF + 7];
    }
    wave_fence();   // idxbuf writes ordered before any idxbuf read

    const float bout0 = bout[0];

    // ---- per-thread gate columns: hid = l15*4 + cg, cg = 0..3 ----
    float br4[4], bz4[4], bni4[4], bhn4[4], w0n24[4], w0r24[4], w0z24[4];
    #pragma unroll
    for (int cg = 0; cg < 4; ++cg) {
        const int hid = l15 * 4 + cg;
        w0r24[cg] = NL2E * Wih[(size_t)hid * INSZ];
        w0z24[cg] = NL2E * Wih[(size_t)(HID + hid) * INSZ];
        w0n24[cg] = TL2E * Wih[(size_t)(2 * HID + hid) * INSZ];
        br4[cg]  = NL2E * (bih[hid] + bhh[hid]) + w0r24[cg] * bout0;
        bz4[cg]  = NL2E * (bih[HID + hid] + bhh[HID + hid]) + w0z24[cg] * bout0;
        bni4[cg] = TL2E * bih[2 * HID + hid] + w0n24[cg] * bout0;
        bhn4[cg] = TL2E * bhh[2 * HID + hid];
    }

    // ---- B fragments. Column map col(l15)=l15*4+cg per cg-group.
    //      r,z gates carry the rank-1 fold Whh + w0 (x) wout. ----
    bf16x8 Bf[3][4][2];   // 96 VGPR
    bf16x8 BX[3][4];      // 48 VGPR
    bf16x8 BO[2];         // 8 VGPR
    #pragma unroll
    for (int gate = 0; gate < 3; ++gate) {
        const float s = (gate < 2) ? NL2E : TL2E;
        #pragma unroll
        for (int cg = 0; cg < 4; ++cg) {
            const int hid = l15 * 4 + cg;
            const float wf = (gate == 0) ? Wih[(size_t)hid * INSZ]
                          : (gate == 1) ? Wih[(size_t)(HID + hid) * INSZ] : 0.0f;
            const float* wr = Whh + (size_t)(gate * HID + hid) * HID;
            #pragma unroll
            for (int ks = 0; ks < 2; ++ks) {
                float4 lo = *(const float4*)(wr + ks * 32 + quad * 8);
                float4 hi = *(const float4*)(wr + ks * 32 + quad * 8 + 4);
                float4 wl = *(const float4*)(Wout + ks * 32 + quad * 8);
                float4 wh = *(const float4*)(Wout + ks * 32 + quad * 8 + 4);
                lo.x = fmaf(wf, wl.x, lo.x); lo.y = fmaf(wf, wl.y, lo.y);
                lo.z = fmaf(wf, wl.z, lo.z); lo.w = fmaf(wf, wl.w, lo.w);
                hi.x = fmaf(wf, wh.x, hi.x); hi.y = fmaf(wf, wh.y, hi.y);
                hi.z = fmaf(wf, wh.z, hi.z); hi.w = fmaf(wf, wh.w, hi.w);
                Bf[gate][cg][ks] = mk_bf8(lo, hi, s);
            }
            const float* wx = Wih + (size_t)(gate * HID + hid) * INSZ + 1 + quad * 8;
            union { unsigned u[4]; bf16x8 v; } f;
            #pragma unroll
            for (int p = 0; p < 4; ++p)
                f.u[p] = cvt_pk_bf16(wx[2 * p] * s, wx[2 * p + 1] * s);
            BX[gate][cg] = f.v;
        }
    }
    #pragma unroll
    for (int ks = 0; ks < 2; ++ks) {
        const float* src = Wout + ks * 32 + quad * 8;
        union { unsigned u[4]; bf16x8 v; } f;
        #pragma unroll
        for (int p = 0; p < 4; ++p)
            f.u[p] = cvt_pk_bf16(src[2 * p], src[2 * p + 1]);
        BO[ks] = f.v;
    }

    // ---- out store bases (rows quad*4+rr); lanes l15==0 store ----
    size_t sb[4];
    #pragma unroll
    for (int rr = 0; rr < 4; ++rr) {
        int cell = cell0 + quad * 4 + rr;
        int b = cell / NN, n = cell - b * NN;
        sb[rr] = (size_t)b * FC * NN + n;
    }
    const bool storer = (l15 == 0);

    // ---- h0: 16 f32/thread (4 rows x 4 cgs) + bf16 Hbuf ----
    float hold[16];                       // hold[cg*4+reg]
    float x0v[4];
    #pragma unroll
    for (int reg = 0; reg < 4; ++reg) {
        float4 h4 = *(const float4*)(hn0 + ((size_t)cell0 + quad * 4 + reg) * HID + l15 * 4);
        hold[0 + reg] = h4.x; hold[4 + reg] = h4.y;
        hold[8 + reg] = h4.z; hold[12 + reg] = h4.w;
        *(uint2*)&Hbuf[(quad * 4 + reg) * AST + l15 * 4] =
            make_uint2(cvt_pk_bf16(h4.x, h4.y), cvt_pk_bf16(h4.z, h4.w));
        x0v[reg] = xn[cell0 + quad * 4 + reg];
    }

    // ---- Xt staging: lane covers (row = lane>>2, k = (lane&3)*8..+7) ----
    const int r4 = lane >> 2, kq = (lane & 3) * 8;
    {
        int idx = idxbuf[r4];
        float4 ea = *(const float4*)(emb + (size_t)idx * EMBD + kq);
        float4 eb = *(const float4*)(emb + (size_t)idx * EMBD + kq + 4);
        union { unsigned u[4]; bf16x8 v; } f;
        f.u[0] = cvt_pk_bf16(ea.x, ea.y); f.u[1] = cvt_pk_bf16(ea.z, ea.w);
        f.u[2] = cvt_pk_bf16(eb.x, eb.y); f.u[3] = cvt_pk_bf16(eb.z, eb.w);
        *(bf16x8*)&Xt[0][r4 * XST + kq] = f.v;
    }

    const f32x4 z4 = {0.f, 0.f, 0.f, 0.f};
    f32x4 ao;

    // one step: MFMAs for all 4 cg groups + gates; x feedback via ao
    auto STEP = [&](const unsigned short* Xc, bool peel) {
        wave_fence();   // order: prior h/X writes BEFORE these reads
        const bf16x8 a0 = *(const bf16x8*)&Hbuf[l15 * AST + quad * 8];
        const bf16x8 a1 = *(const bf16x8*)&Hbuf[l15 * AST + 32 + quad * 8];
        const bf16x8 x0 = *(const bf16x8*)&Xc[l15 * XST + quad * 8];
        ao = __builtin_amdgcn_mfma_f32_16x16x32_bf16(a0, BO[0], z4, 0, 0, 0);
        ao = __builtin_amdgcn_mfma_f32_16x16x32_bf16(a1, BO[1], ao, 0, 0, 0);
        #pragma unroll
        for (int cg = 0; cg < 4; ++cg) {
            f32x4 ar = __builtin_amdgcn_mfma_f32_16x16x32_bf16(x0, BX[0][cg], z4, 0, 0, 0);
            ar = __builtin_amdgcn_mfma_f32_16x16x32_bf16(a0, Bf[0][cg][0], ar, 0, 0, 0);
            ar = __builtin_amdgcn_mfma_f32_16x16x32_bf16(a1, Bf[0][cg][1], ar, 0, 0, 0);
            f32x4 az = __builtin_amdgcn_mfma_f32_16x16x32_bf16(x0, BX[1][cg], z4, 0, 0, 0);
            az = __builtin_amdgcn_mfma_f32_16x16x32_bf16(a0, Bf[1][cg][0], az, 0, 0, 0);
            az = __builtin_amdgcn_mfma_f32_16x16x32_bf16(a1, Bf[1][cg][1], az, 0, 0, 0);
            f32x4 ani = __builtin_amdgcn_mfma_f32_16x16x32_bf16(x0, BX[2][cg], z4, 0, 0, 0);
            f32x4 ang = __builtin_amdgcn_mfma_f32_16x16x32_bf16(a0, Bf[2][cg][0], z4, 0, 0, 0);
            ang = __builtin_amdgcn_mfma_f32_16x16x32_bf16(a1, Bf[2][cg][1], ang, 0, 0, 0);
            #pragma unroll
            for (int reg = 0; reg < 4; ++reg) {
                float arv = ar[reg] + br4[cg];
                float azv = az[reg] + bz4[cg];
                float xnv = ao[reg];
                if (peel) {   // t=0: real x from xn; undo the rank-1 fold
                    float xc = x0v[reg] - bout0 - ao[reg];
                    arv = fmaf(w0r24[cg], xc, arv);
                    azv = fmaf(w0z24[cg], xc, azv);
                    xnv = x0v[reg] - bout0;
                }
                float r = __builtin_amdgcn_rcpf(1.0f + __builtin_amdgcn_exp2f(arv));
                float z = __builtin_amdgcn_rcpf(1.0f + __builtin_amdgcn_exp2f(azv));
                float v = fmaf(r, ang[reg] + bhn4[cg],
                               fmaf(w0n24[cg], xnv, ani[reg] + bni4[cg]));
                float e = __builtin_amdgcn_exp2f(v);   // saturates: no clamp
                float nv = fmaf(-2.0f, __builtin_amdgcn_rcpf(e + 1.0f), 1.0f);
                hold[cg * 4 + reg] = fmaf(z, hold[cg * 4 + reg] - nv, nv);
            }
        }
        wave_fence();   // order: a0/a1 reads BEFORE the h write-back
        #pragma unroll
        for (int reg = 0; reg < 4; ++reg)
            *(uint2*)&Hbuf[(quad * 4 + reg) * AST + l15 * 4] =
                make_uint2(cvt_pk_bf16(hold[reg], hold[4 + reg]),
                           cvt_pk_bf16(hold[8 + reg], hold[12 + reg]));
    };

    auto STAGE_X = [&](int tt, unsigned short* dst) {
        int idx = idxbuf[tt * CPW + r4];
        float4 ea = *(const float4*)(emb + (size_t)idx * EMBD + kq);
        float4 eb = *(const float4*)(emb + (size_t)idx * EMBD + kq + 4);
        union { unsigned u[4]; bf16x8 v; } f;
        f.u[0] = cvt_pk_bf16(ea.x, ea.y); f.u[1] = cvt_pk_bf16(ea.z, ea.w);
        f.u[2] = cvt_pk_bf16(eb.x, eb.y); f.u[3] = cvt_pk_bf16(eb.z, eb.w);
        *(bf16x8*)&dst[r4 * XST + kq] = f.v;
    };

    // ---- peeled t=0 ----
    STEP(Xt[0], true);
    STAGE_X(1, Xt[1]);

    // ---- main loop: no barriers at all ----
    unsigned short* xcur = Xt[1];
    unsigned short* xnxt = Xt[0];
    for (int t = 1; t < FC; ++t) {
        STEP(xcur, false);
        if (storer) {
            #pragma unroll
            for (int rr = 0; rr < 4; ++rr)
                out[sb[rr] + (size_t)(t - 1) * NN] = ao[rr] + bout0;
        }
        STAGE_X(t + 1, xnxt);   // row FC dups FC-1; harmless at t=FC-1
        unsigned short* tmp = xcur; xcur = xnxt; xnxt = tmp;
    }

    // ---- epilogue: out(FC-1) from final h in Hbuf ----
    {
        wave_fence();   // order: final h write-back BEFORE these reads
        const bf16x8 a0 = *(const bf16x8*)&Hbuf[l15 * AST + quad * 8];
        const bf16x8 a1 = *(const bf16x8*)&Hbuf[l15 * AST + 32 + quad * 8];
        f32x4 o = __builtin_amdgcn_mfma_f32_16x16x32_bf16(a0, BO[0], z4, 0, 0, 0);
        o = __builtin_amdgcn_mfma_f32_16x16x32_bf16(a1, BO[1], o, 0, 0, 0);
        if (storer) {
            #pragma unroll
            for (int rr = 0; rr < 4; ++rr)
                out[sb[rr] + (size_t)(FC - 1) * NN] = o[rr] + bout0;
        }
    }
}

extern "C" void kernel_launch(void* const* d_in, const int* in_sizes, int n_in,
                              void* d_out, int out_size, void* d_ws, size_t ws_size,
                              hipStream_t stream) {
    (void)in_sizes; (void)n_in; (void)out_size; (void)d_ws; (void)ws_size;
    const float* X    = (const float*)d_in[0];
    const float* hn   = (const float*)d_in[1];
    const float* xn   = (const float*)d_in[2];
    const float* emb  = (const float*)d_in[3];
    const float* Wih  = (const float*)d_in[4];
    const float* Whh  = (const float*)d_in[5];
    const float* bih  = (const float*)d_in[6];
    const float* bhh  = (const float*)d_in[7];
    const float* Wout = (const float*)d_in[8];
    const float* bout = (const float*)d_in[9];
    float* out = (float*)d_out;

    const int blocks = (BB * NN) / CPW;   // 4000 one-wave blocks
    gru_decoder<<<blocks, 64, 0, stream>>>(X, hn, xn, emb, Wih, Whh,
                                           bih, bhh, Wout, bout, out);
}

// Round 9
// 272.006 us; speedup vs baseline: 1.0376x; 1.0376x over previous
//
#include <hip/hip_runtime.h>
#include <math.h>

// Problem constants
#define BB   64
#define FC   24
#define NN   1000
#define HID  64
#define EMBD 32
#define TT   48
#define FF   8
#define INSZ 33

// One wave (64 threads) per block; wave owns CPW cells x all 64 hid cols.
#define CPW  16
#define AST  72     // Hbuf stride in bf16 elems (144 B rows, 16B-aligned)
#define XST  40     // Xt stride in bf16 elems (80 B rows, 16B-aligned)

#define NL2E (-1.4426950408889634f)   // -log2(e): folded into r,z weights
#define TL2E ( 2.8853900817779268f)   // 2*log2(e): folded into n weights

typedef __attribute__((ext_vector_type(8))) short bf16x8;
typedef __attribute__((ext_vector_type(4))) float f32x4;

// packed RNE f32->bf16: lo16 = bf16(a), hi16 = bf16(b)
static __device__ __forceinline__ unsigned cvt_pk_bf16(float a, float b) {
    unsigned r;
    asm("v_cvt_pk_bf16_f32 %0, %1, %2" : "=v"(r) : "v"(a), "v"(b));
    return r;
}
static __device__ __forceinline__ bf16x8 mk_bf8(float4 lo, float4 hi, float s) {
    union { unsigned u[4]; bf16x8 v; } r;
    r.u[0] = cvt_pk_bf16(lo.x * s, lo.y * s);
    r.u[1] = cvt_pk_bf16(lo.z * s, lo.w * s);
    r.u[2] = cvt_pk_bf16(hi.x * s, hi.y * s);
    r.u[3] = cvt_pk_bf16(hi.z * s, hi.w * s);
    return r.v;
}

// COMPILER-ONLY fence, zero ISA instructions (R8-verified). Same-wave DS
// ops execute in order in hardware; this stops TBAA-based reordering of
// mixed-type LDS accesses.
static __device__ __forceinline__ void wave_fence() {
    asm volatile("" ::: "memory");
    __builtin_amdgcn_sched_barrier(0);
}

// NO s_barrier: all LDS is wave-private; ordering = in-order DS + fences.
__global__ __launch_bounds__(64) __attribute__((amdgpu_waves_per_eu(2)))
void gru_decoder(
    const float* __restrict__ X,    // [B][TT][N][F]
    const float* __restrict__ hn0,  // [B*N][HID]
    const float* __restrict__ xn,   // [B][N][1]
    const float* __restrict__ emb,  // [NEMB][EMBD]
    const float* __restrict__ Wih,  // [3*HID][INSZ]
    const float* __restrict__ Whh,  // [3*HID][HID]
    const float* __restrict__ bih,  // [3*HID]
    const float* __restrict__ bhh,  // [3*HID]
    const float* __restrict__ Wout, // [1][HID]
    const float* __restrict__ bout, // [1]
    float* __restrict__ out)        // [B][FC][N][1]
{
    __shared__ __align__(16) unsigned short Hbuf[CPW * AST];       // 2304 B
    __shared__ __align__(16) unsigned short Xt[2][CPW * XST];      // 2560 B
    __shared__ __align__(16) unsigned short WX[12 * 64 * 8];       // 12288 B
    __shared__ unsigned short idxbuf[(FC + 1) * CPW];              // 800 B

    const int lane = threadIdx.x;      // one wave per block
    const int quad = lane >> 4;
    const int l15  = lane & 15;
    const int cell0 = blockIdx.x * CPW;

    // ---- stage idx for steps 0..FC (row FC dups FC-1) ----
    for (int e = lane; e < (FC + 1) * CPW; e += 64) {
        int t = e >> 4, m = e & 15;
        int tt = (t < FC) ? t : FC - 1;
        int cell = cell0 + m;
        int b = cell / NN, n = cell - b * NN;
        idxbuf[e] = (unsigned short)(int)X[(((size_t)b * TT + tt) * NN + n) * FF + 7];
    }

    const float bout0 = bout[0];

    // ---- per-thread gate columns: hid = l15*4 + cg, cg = 0..3 ----
    float br4[4], bz4[4], bni4[4], bhn4[4], w0n24[4], w0r24[4], w0z24[4];
    #pragma unroll
    for (int cg = 0; cg < 4; ++cg) {
        const int hid = l15 * 4 + cg;
        w0r24[cg] = NL2E * Wih[(size_t)hid * INSZ];
        w0z24[cg] = NL2E * Wih[(size_t)(HID + hid) * INSZ];
        w0n24[cg] = TL2E * Wih[(size_t)(2 * HID + hid) * INSZ];
        br4[cg]  = NL2E * (bih[hid] + bhh[hid]) + w0r24[cg] * bout0;
        bz4[cg]  = NL2E * (bih[HID + hid] + bhh[HID + hid]) + w0z24[cg] * bout0;
        bni4[cg] = TL2E * bih[2 * HID + hid] + w0n24[cg] * bout0;
        bhn4[cg] = TL2E * bhh[2 * HID + hid];
    }

    // ---- Whh^T fragments in regs (96 VGPR). r,z gates carry the rank-1
    //      fold Whh + w0 (x) wout. Column map col(l15) = l15*4 + cg. ----
    bf16x8 Bf[3][4][2];
    #pragma unroll
    for (int gate = 0; gate < 3; ++gate) {
        const float s = (gate < 2) ? NL2E : TL2E;
        #pragma unroll
        for (int cg = 0; cg < 4; ++cg) {
            const int hid = l15 * 4 + cg;
            const float wf = (gate == 0) ? Wih[(size_t)hid * INSZ]
                          : (gate == 1) ? Wih[(size_t)(HID + hid) * INSZ] : 0.0f;
            const float* wr = Whh + (size_t)(gate * HID + hid) * HID;
            #pragma unroll
            for (int ks = 0; ks < 2; ++ks) {
                float4 lo = *(const float4*)(wr + ks * 32 + quad * 8);
                float4 hi = *(const float4*)(wr + ks * 32 + quad * 8 + 4);
                float4 wl = *(const float4*)(Wout + ks * 32 + quad * 8);
                float4 wh = *(const float4*)(Wout + ks * 32 + quad * 8 + 4);
                lo.x = fmaf(wf, wl.x, lo.x); lo.y = fmaf(wf, wl.y, lo.y);
                lo.z = fmaf(wf, wl.z, lo.z); lo.w = fmaf(wf, wl.w, lo.w);
                hi.x = fmaf(wf, wh.x, hi.x); hi.y = fmaf(wf, wh.y, hi.y);
                hi.z = fmaf(wf, wh.z, hi.z); hi.w = fmaf(wf, wh.w, hi.w);
                Bf[gate][cg][ks] = mk_bf8(lo, hi, s);
            }
            // Wih embedding fragment (cols 1..32) -> wave-private LDS
            const float* wx = Wih + (size_t)(gate * HID + hid) * INSZ + 1 + quad * 8;
            union { unsigned u[4]; bf16x8 v; } f;
            #pragma unroll
            for (int p = 0; p < 4; ++p)
                f.u[p] = cvt_pk_bf16(wx[2 * p] * s, wx[2 * p + 1] * s);
            *(bf16x8*)&WX[(gate * 4 + cg) * 512 + lane * 8] = f.v;
        }
    }
    // Wout replicated to all 16 B-cols (8 VGPRs): ao = h.wout per row
    bf16x8 BO[2];
    #pragma unroll
    for (int ks = 0; ks < 2; ++ks) {
        const float* src = Wout + ks * 32 + quad * 8;
        union { unsigned u[4]; bf16x8 v; } f;
        #pragma unroll
        for (int p = 0; p < 4; ++p)
            f.u[p] = cvt_pk_bf16(src[2 * p], src[2 * p + 1]);
        BO[ks] = f.v;
    }

    // ---- out store bases as 32-bit (max idx 1.54M); lanes l15==0 store ----
    int ob4[4];
    #pragma unroll
    for (int rr = 0; rr < 4; ++rr) {
        int cell = cell0 + quad * 4 + rr;
        int b = cell / NN, n = cell - b * NN;
        ob4[rr] = b * FC * NN + n;
    }
    const bool storer = (l15 == 0);

    // ---- h0: 16 f32/thread (4 rows x 4 cgs) + bf16 Hbuf ----
    float hold[16];                       // hold[cg*4+reg]
    float x0v[4];
    #pragma unroll
    for (int reg = 0; reg < 4; ++reg) {
        float4 h4 = *(const float4*)(hn0 + ((size_t)cell0 + quad * 4 + reg) * HID + l15 * 4);
        hold[0 + reg] = h4.x; hold[4 + reg] = h4.y;
        hold[8 + reg] = h4.z; hold[12 + reg] = h4.w;
        *(uint2*)&Hbuf[(quad * 4 + reg) * AST + l15 * 4] =
            make_uint2(cvt_pk_bf16(h4.x, h4.y), cvt_pk_bf16(h4.z, h4.w));
        x0v[reg] = xn[cell0 + quad * 4 + reg];
    }
    wave_fence();   // idx/WX/Hbuf writes ordered before reads below

    // ---- Xt staging: lane covers (row = lane>>2, k = (lane&3)*8..+7) ----
    const int r4 = lane >> 2, kq = (lane & 3) * 8;
    {
        int idx = idxbuf[r4];
        float4 ea = *(const float4*)(emb + (size_t)idx * EMBD + kq);
        float4 eb = *(const float4*)(emb + (size_t)idx * EMBD + kq + 4);
        union { unsigned u[4]; bf16x8 v; } f;
        f.u[0] = cvt_pk_bf16(ea.x, ea.y); f.u[1] = cvt_pk_bf16(ea.z, ea.w);
        f.u[2] = cvt_pk_bf16(eb.x, eb.y); f.u[3] = cvt_pk_bf16(eb.z, eb.w);
        *(bf16x8*)&Xt[0][r4 * XST + kq] = f.v;
    }

    const f32x4 z4 = {0.f, 0.f, 0.f, 0.f};
    f32x4 ao;

    // one step: MFMAs for all 4 cg groups + gates; x feedback via ao
    auto STEP = [&](const unsigned short* Xc, bool peel) {
        wave_fence();   // order: prior h/X writes BEFORE these reads
        const bf16x8 a0 = *(const bf16x8*)&Hbuf[l15 * AST + quad * 8];
        const bf16x8 a1 = *(const bf16x8*)&Hbuf[l15 * AST + 32 + quad * 8];
        const bf16x8 x0 = *(const bf16x8*)&Xc[l15 * XST + quad * 8];
        ao = __builtin_amdgcn_mfma_f32_16x16x32_bf16(a0, BO[0], z4, 0, 0, 0);
        ao = __builtin_amdgcn_mfma_f32_16x16x32_bf16(a1, BO[1], ao, 0, 0, 0);
        #pragma unroll
        for (int cg = 0; cg < 4; ++cg) {
            const bf16x8 bx0 = *(const bf16x8*)&WX[(0 * 4 + cg) * 512 + lane * 8];
            const bf16x8 bx1 = *(const bf16x8*)&WX[(1 * 4 + cg) * 512 + lane * 8];
            const bf16x8 bx2 = *(const bf16x8*)&WX[(2 * 4 + cg) * 512 + lane * 8];
            f32x4 ar = __builtin_amdgcn_mfma_f32_16x16x32_bf16(x0, bx0, z4, 0, 0, 0);
            ar = __builtin_amdgcn_mfma_f32_16x16x32_bf16(a0, Bf[0][cg][0], ar, 0, 0, 0);
            ar = __builtin_amdgcn_mfma_f32_16x16x32_bf16(a1, Bf[0][cg][1], ar, 0, 0, 0);
            f32x4 az = __builtin_amdgcn_mfma_f32_16x16x32_bf16(x0, bx1, z4, 0, 0, 0);
            az = __builtin_amdgcn_mfma_f32_16x16x32_bf16(a0, Bf[1][cg][0], az, 0, 0, 0);
            az = __builtin_amdgcn_mfma_f32_16x16x32_bf16(a1, Bf[1][cg][1], az, 0, 0, 0);
            f32x4 ani = __builtin_amdgcn_mfma_f32_16x16x32_bf16(x0, bx2, z4, 0, 0, 0);
            f32x4 ang = __builtin_amdgcn_mfma_f32_16x16x32_bf16(a0, Bf[2][cg][0], z4, 0, 0, 0);
            ang = __builtin_amdgcn_mfma_f32_16x16x32_bf16(a1, Bf[2][cg][1], ang, 0, 0, 0);
            #pragma unroll
            for (int reg = 0; reg < 4; ++reg) {
                float arv = ar[reg] + br4[cg];
                float azv = az[reg] + bz4[cg];
                float xnv = ao[reg];
                if (peel) {   // t=0: real x from xn; undo the rank-1 fold
                    float xc = x0v[reg] - bout0 - ao[reg];
                    arv = fmaf(w0r24[cg], xc, arv);
                    azv = fmaf(w0z24[cg], xc, azv);
                    xnv = x0v[reg] - bout0;
                }
                float r = __builtin_amdgcn_rcpf(1.0f + __builtin_amdgcn_exp2f(arv));
                float z = __builtin_amdgcn_rcpf(1.0f + __builtin_amdgcn_exp2f(azv));
                float v = fmaf(r, ang[reg] + bhn4[cg],
                               fmaf(w0n24[cg], xnv, ani[reg] + bni4[cg]));
                float e = __builtin_amdgcn_exp2f(v);   // saturates: no clamp
                float nv = fmaf(-2.0f, __builtin_amdgcn_rcpf(e + 1.0f), 1.0f);
                hold[cg * 4 + reg] = fmaf(z, hold[cg * 4 + reg] - nv, nv);
            }
        }
        wave_fence();   // order: a0/a1 reads BEFORE the h write-back
        #pragma unroll
        for (int reg = 0; reg < 4; ++reg)
            *(uint2*)&Hbuf[(quad * 4 + reg) * AST + l15 * 4] =
                make_uint2(cvt_pk_bf16(hold[reg], hold[4 + reg]),
                           cvt_pk_bf16(hold[8 + reg], hold[12 + reg]));
    };

    auto STAGE_X = [&](int tt, unsigned short* dst) {
        int idx = idxbuf[tt * CPW + r4];
        float4 ea = *(const float4*)(emb + (size_t)idx * EMBD + kq);
        float4 eb = *(const float4*)(emb + (size_t)idx * EMBD + kq + 4);
        union { unsigned u[4]; bf16x8 v; } f;
        f.u[0] = cvt_pk_bf16(ea.x, ea.y); f.u[1] = cvt_pk_bf16(ea.z, ea.w);
        f.u[2] = cvt_pk_bf16(eb.x, eb.y); f.u[3] = cvt_pk_bf16(eb.z, eb.w);
        *(bf16x8*)&dst[r4 * XST + kq] = f.v;
    };

    // ---- peeled t=0 ----
    STEP(Xt[0], true);
    STAGE_X(1, Xt[1]);

    // ---- main loop: no barriers at all ----
    unsigned short* xcur = Xt[1];
    unsigned short* xnxt = Xt[0];
    for (int t = 1; t < FC; ++t) {
        STEP(xcur, false);
        if (storer) {
            #pragma unroll
            for (int rr = 0; rr < 4; ++rr)
                out[ob4[rr] + (t - 1) * NN] = ao[rr] + bout0;
        }
        STAGE_X(t + 1, xnxt);   // row FC dups FC-1; harmless at t=FC-1
        unsigned short* tmp = xcur; xcur = xnxt; xnxt = tmp;
    }

    // ---- epilogue: out(FC-1) from final h in Hbuf ----
    {
        wave_fence();   // order: final h write-back BEFORE these reads
        const bf16x8 a0 = *(const bf16x8*)&Hbuf[l15 * AST + quad * 8];
        const bf16x8 a1 = *(const bf16x8*)&Hbuf[l15 * AST + 32 + quad * 8];
        f32x4 o = __builtin_amdgcn_mfma_f32_16x16x32_bf16(a0, BO[0], z4, 0, 0, 0);
        o = __builtin_amdgcn_mfma_f32_16x16x32_bf16(a1, BO[1], o, 0, 0, 0);
        if (storer) {
            #pragma unroll
            for (int rr = 0; rr < 4; ++rr)
                out[ob4[rr] + (FC - 1) * NN] = o[rr] + bout0;
        }
    }
}

extern "C" void kernel_launch(void* const* d_in, const int* in_sizes, int n_in,
                              void* d_out, int out_size, void* d_ws, size_t ws_size,
                              hipStream_t stream) {
    (void)in_sizes; (void)n_in; (void)out_size; (void)d_ws; (void)ws_size;
    const float* X    = (const float*)d_in[0];
    const float* hn   = (const float*)d_in[1];
    const float* xn   = (const float*)d_in[2];
    const float* emb  = (const float*)d_in[3];
    const float* Wih  = (const float*)d_in[4];
    const float* Whh  = (const float*)d_in[5];
    const float* bih  = (const float*)d_in[6];
    const float* bhh  = (const float*)d_in[7];
    const float* Wout = (const float*)d_in[8];
    const float* bout = (const float*)d_in[9];
    float* out = (float*)d_out;

    const int blocks = (BB * NN) / CPW;   // 4000 one-wave blocks
    gru_decoder<<<blocks, 64, 0, stream>>>(X, hn, xn, emb, Wih, Whh,
                                           bih, bhh, Wout, bout, out);
}